// Round 11
// baseline (2049.332 us; speedup 1.0000x reference)
//
#include <hip/hip_runtime.h>

#define N_NODES 200000
#define CDIM 128
#define NSCALE 6
#define NEP 100000
#define NEL 25000
#define NCLS 14
#define NCHUNK 196   // ceil(200000/1024)
#define MROWS 64     // layer_k tile rows

typedef unsigned short u16;
typedef unsigned int u32;

using fragAB = __attribute__((ext_vector_type(8))) short;  // 8 bf16
using fragC  = __attribute__((ext_vector_type(4))) float;  // 4 fp32

enum { P_PLAIN = 0, P_TWO = 1, P_META = 2 };
enum { E_GN = 1, E_RELU = 2 };

__device__ __forceinline__ float4 ld4(const float* p) { return *(const float4*)p; }

__device__ __forceinline__ u16 f2bf(float f) {
  u32 u = __builtin_bit_cast(u32, f);
  u = (u + 0x7fff + ((u >> 16) & 1)) >> 16;
  return (u16)u;
}
__device__ __forceinline__ u32 pk2(float a, float b) {
  return (u32)f2bf(a) | ((u32)f2bf(b) << 16);
}
__device__ __forceinline__ float bflo(u32 u) { return __builtin_bit_cast(float, u << 16); }
__device__ __forceinline__ float bfhi(u32 u) { return __builtin_bit_cast(float, u & 0xffff0000u); }

__device__ __forceinline__ void acc16(float* s, uint4 a, uint4 b) {
  s[0] += bflo(a.x); s[1] += bfhi(a.x); s[2]  += bflo(a.y); s[3]  += bfhi(a.y);
  s[4] += bflo(a.z); s[5] += bfhi(a.z); s[6]  += bflo(a.w); s[7]  += bfhi(a.w);
  s[8] += bflo(b.x); s[9] += bfhi(b.x); s[10] += bflo(b.y); s[11] += bfhi(b.y);
  s[12] += bflo(b.z); s[13] += bfhi(b.z); s[14] += bflo(b.w); s[15] += bfhi(b.w);
}

__host__ __device__ constexpr int idx_base(int c) {
  return (c < 12) ? c * NEP : 12 * NEP + (c - 12) * NEL;
}

// weight slot table (prep_k layout): 0 in2, 1 seg2, 2-5 ctr, 6-9 ctr2, 10-13 left,
// 14-17 right, 18-41 pre[i*6+s], 42-65 suc[i*6+s], 66 meta
__device__ __forceinline__ int wslot(int li, int c) {
  if (c < 0)  return 2 + li;
  if (c < 6)  return 18 + li * 6 + c;
  if (c < 12) return 42 + li * 6 + (c - 6);
  return (c == 12) ? (10 + li) : (14 + li);
}

// ================= prologue MFMA GEMM (a/b/meta branches) =================
template<int PRO, int EPI>
__global__ __launch_bounds__(256)
void mm_k(int M, int Kp,
          const float* __restrict__ Af, const float* __restrict__ A2f,
          const float* __restrict__ e0, const float* __restrict__ e1, const float* __restrict__ e2,
          const u16* __restrict__ Wt,
          float* __restrict__ Y, u16* __restrict__ Yb,
          const float* __restrict__ gn_g, const float* __restrict__ gn_b)
{
  constexpr int LSTR = 56;
  __shared__ u16 As[128 * LSTR];
  __shared__ u16 Bs[128 * LSTR];

  const int tid = threadIdx.x;
  const int lane = tid & 63, wid = tid >> 6;
  const int wm = (wid >> 1) * 64, wn = (wid & 1) * 64;
  const int q = lane >> 4, l16 = lane & 15;
  const int row0 = blockIdx.x * 128;
  const int srow = tid >> 1, shalf = tid & 1;

  fragC acc[4][4];
  #pragma unroll
  for (int i = 0; i < 4; i++)
    #pragma unroll
    for (int j = 0; j < 4; j++)
      #pragma unroll
      for (int e = 0; e < 4; e++) acc[i][j][e] = 0.0f;

  const int sgrow = row0 + srow;
  const bool svalid = (sgrow < M);
  float x0 = 0.f, x1 = 0.f, mx = 0.f, my = 0.f, mc = 0.f, mi = 0.f;
  if constexpr (PRO == P_TWO) {
    if (svalid) { x0 = Af[(size_t)sgrow * 2]; x1 = Af[(size_t)sgrow * 2 + 1]; }
  }
  if constexpr (PRO == P_META) {
    if (svalid) { mx = e0[(size_t)sgrow * 2]; my = e0[(size_t)sgrow * 2 + 1]; mc = e1[sgrow]; mi = e2[sgrow]; }
  }

  const int nk = Kp >> 5;
  for (int kt = 0; kt < nk; ++kt) {
    const int k0 = kt * 32 + shalf * 16;
    {
      u16* adst = &As[srow * LSTR + shalf * 16];
      float v[16];
      #pragma unroll
      for (int j = 0; j < 16; j++) v[j] = 0.f;
      if constexpr (PRO == P_TWO) {
        #pragma unroll
        for (int j0 = 0; j0 < 16; j0 += 4) {
          float4 wa = ld4(e0 + k0 + j0);
          float4 wb = ld4(e0 + 128 + k0 + j0);
          float4 bb = ld4(e1 + k0 + j0);
          v[j0]     = fmaxf(0.f, fmaf(x0, wa.x, fmaf(x1, wb.x, bb.x)));
          v[j0 + 1] = fmaxf(0.f, fmaf(x0, wa.y, fmaf(x1, wb.y, bb.y)));
          v[j0 + 2] = fmaxf(0.f, fmaf(x0, wa.z, fmaf(x1, wb.z, bb.z)));
          v[j0 + 3] = fmaxf(0.f, fmaf(x0, wa.w, fmaf(x1, wb.w, bb.w)));
        }
      } else { // P_META
        if (svalid) {
          if (k0 < 128) {
            const float* sa = Af + (size_t)sgrow * 128 + k0;
            const float* sb = A2f + (size_t)sgrow * 128 + k0;
            #pragma unroll
            for (int j0 = 0; j0 < 16; j0 += 4) {
              float4 a = ld4(sa + j0), b = ld4(sb + j0);
              v[j0]     = fmaxf(0.f, a.x + b.x);
              v[j0 + 1] = fmaxf(0.f, a.y + b.y);
              v[j0 + 2] = fmaxf(0.f, a.z + b.z);
              v[j0 + 3] = fmaxf(0.f, a.w + b.w);
            }
          } else {
            #pragma unroll
            for (int j = 0; j < 16; j++) {
              const int kk = k0 + j - 128;
              v[j] = (kk == 0) ? mx : (kk == 1) ? my : (kk == 2) ? mc : (kk == 3) ? mi : 0.f;
            }
          }
        }
      }
      u32 p[8];
      #pragma unroll
      for (int j = 0; j < 8; j++) p[j] = pk2(v[2 * j], v[2 * j + 1]);
      *(uint4*)adst = make_uint4(p[0], p[1], p[2], p[3]);
      *(uint4*)(adst + 8) = make_uint4(p[4], p[5], p[6], p[7]);
    }
    {
      const u16* s = Wt + (size_t)srow * Kp + k0;
      uint4 b0 = *(const uint4*)s, b1 = *(const uint4*)(s + 8);
      u16* bdst = &Bs[srow * LSTR + shalf * 16];
      *(uint4*)bdst = b0; *(uint4*)(bdst + 8) = b1;
    }
    __syncthreads();
    fragAB af[4], bf[4];
    #pragma unroll
    for (int t = 0; t < 4; t++) af[t] = *(const fragAB*)&As[(wm + t * 16 + l16) * LSTR + q * 8];
    #pragma unroll
    for (int t = 0; t < 4; t++) bf[t] = *(const fragAB*)&Bs[(wn + t * 16 + l16) * LSTR + q * 8];
    #pragma unroll
    for (int mt = 0; mt < 4; mt++)
      #pragma unroll
      for (int nt = 0; nt < 4; nt++)
        acc[mt][nt] = __builtin_amdgcn_mfma_f32_16x16x32_bf16(af[mt], bf[nt], acc[mt][nt], 0, 0, 0);
    __syncthreads();
  }

  // GN epilogue
  __shared__ float2 red[128][2];
  __shared__ float2 stats[128];
  #pragma unroll
  for (int mt = 0; mt < 4; mt++)
    #pragma unroll
    for (int r = 0; r < 4; r++) {
      float s1 = acc[mt][0][r] + acc[mt][1][r] + acc[mt][2][r] + acc[mt][3][r];
      float s2 = acc[mt][0][r] * acc[mt][0][r] + acc[mt][1][r] * acc[mt][1][r]
               + acc[mt][2][r] * acc[mt][2][r] + acc[mt][3][r] * acc[mt][3][r];
      #pragma unroll
      for (int off = 1; off < 16; off <<= 1) {
        s1 += __shfl_xor(s1, off, 64);
        s2 += __shfl_xor(s2, off, 64);
      }
      if (l16 == 0) red[wm + mt * 16 + q * 4 + r][wid & 1] = make_float2(s1, s2);
    }
  __syncthreads();
  if (tid < 128) {
    const float2 p0 = red[tid][0], p1 = red[tid][1];
    const float m = (p0.x + p1.x) * (1.0f / 128.0f);
    const float var = (p0.y + p1.y) * (1.0f / 128.0f) - m * m;
    stats[tid] = make_float2(m, rsqrtf(var + 1e-5f));
  }
  __syncthreads();
  float gl[4], bl[4];
  #pragma unroll
  for (int nt = 0; nt < 4; nt++) {
    gl[nt] = gn_g[wn + nt * 16 + l16];
    bl[nt] = gn_b[wn + nt * 16 + l16];
  }
  #pragma unroll
  for (int mt = 0; mt < 4; mt++)
    #pragma unroll
    for (int r = 0; r < 4; r++) {
      const int rl = wm + mt * 16 + q * 4 + r;
      const int grow = row0 + rl;
      if (grow >= M) continue;
      const float2 st = stats[rl];
      #pragma unroll
      for (int nt = 0; nt < 4; nt++) {
        const int col = wn + nt * 16 + l16;
        float v = (acc[mt][nt][r] - st.x) * st.y * gl[nt] + bl[nt];
        if constexpr ((EPI & E_RELU) != 0) v = fmaxf(v, 0.f);
        if (Y)  Y[(size_t)grow * 128 + col] = v;
        if (Yb) Yb[(size_t)grow * 128 + col] = f2bf(v);
      }
    }
}

// ================= fused per-layer kernel (64-row tiles) =================
// R10 structure at half tile: LDS ~28.5KB -> 5 blocks/CU (20 waves), doubling
// the independent block streams that hide each other's barrier-drain stalls.
// Carries over: idx-cache + ends table (1-level gather chain), T2 XOR swizzle
// on both tiles, per-kt B staging. acc[2][4] (32 AGPR) fits (256,5) cap.
__global__ __launch_bounds__(256, 5)
void layer_k(const u16* __restrict__ Fin, u16* __restrict__ Fout,
             float* __restrict__ outf,
             const int* __restrict__ ptrs, const int* __restrict__ idxs,
             const u16* __restrict__ Wt, int li,
             const float* __restrict__ g1, const float* __restrict__ b1,
             const float* __restrict__ g2, const float* __restrict__ b2)
{
  __shared__ u16 ldsA[MROWS * 128];    // 16384B, swizzled A tile / feat_mid
  __shared__ u16 Bsb[128 * 32];        // 8192B, swizzled per-kt B chunk; aliases red/stats
  __shared__ u16 ends[NCLS][MROWS];    // 1792B, block-local CSR end offsets
  __shared__ int cbase[NCLS];
  __shared__ int ccnt[NCLS];
  __shared__ int idxC[2][256];         // 2048B, double-buffered edge indices

  float2* red   = (float2*)Bsb;          // [64][2], bytes 0..1023
  float2* stats = (float2*)(Bsb + 512);  // [64],   bytes 1024..1535

  const int tid = threadIdx.x;
  const int lane = tid & 63, wid = tid >> 6;
  const int wm = (wid >> 1) * 32, wn = (wid & 1) * 64;
  const int q = lane >> 4, l16 = lane & 15;
  const int row0 = blockIdx.x * MROWS;
  const int row8 = tid >> 3;          // gather: row within group (0..31)
  const int goff = (tid & 7) * 16;    // gather: channel offset (0..112)

  // XOR-swizzled tile addressing (16B granules; same XOR on every access)
  auto swzA = [&](int row, int colu) -> u16* {
    u32 b = (u32)(row * 256 + colu * 2) ^ ((u32)(row & 7) << 4);
    return (u16*)((char*)ldsA + b);
  };
  auto swzB = [&](int row, int colu) -> u16* {
    u32 b = (u32)(row * 64 + colu * 2) ^ ((((u32)((row >> 1) ^ (row >> 3))) & 3u) << 4);
    return (u16*)((char*)Bsb + b);
  };

  fragC acc[2][4];
  #pragma unroll
  for (int i = 0; i < 2; i++)
    #pragma unroll
    for (int j = 0; j < 4; j++)
      #pragma unroll
      for (int e = 0; e < 4; e++) acc[i][j][e] = 0.0f;

  // ---------- upfront: class bases ----------
  if (tid < NCLS) {
    const int* pc = ptrs + (size_t)tid * (N_NODES + 1);
    const int b = row0 ? pc[row0 - 1] : 0;
    const int hiRow = (row0 + MROWS - 1 < N_NODES) ? (row0 + MROWS - 1) : (N_NODES - 1);
    cbase[tid] = b;
    ccnt[tid] = pc[hiRow] - b;
  }
  __syncthreads();

  // ---------- upfront: ends table + ctr A stage + idx cache cls0 ----------
  #pragma unroll 1
  for (int t = tid; t < NCLS * MROWS; t += 256) {
    const int c = t / MROWS, r = t % MROWS;
    const int grow = row0 + r;
    const int* pc = ptrs + (size_t)c * (N_NODES + 1);
    const int gr = (grow < N_NODES) ? grow : (N_NODES - 1);
    ends[c][r] = (u16)(pc[gr] - cbase[c]);
  }
  {
    const int srow4 = tid >> 2, q4 = tid & 3;   // 64 rows x 4 quarters (32ch)
    const int sgrow = row0 + srow4;
    uint4 a[4];
    #pragma unroll
    for (int j = 0; j < 4; j++) a[j] = make_uint4(0, 0, 0, 0);
    if (sgrow < N_NODES) {
      const u16* s = Fin + (size_t)sgrow * 128 + q4 * 32;
      #pragma unroll
      for (int j = 0; j < 4; j++) a[j] = ((const uint4*)s)[j];
    }
    #pragma unroll
    for (int j = 0; j < 4; j++) *(uint4*)swzA(srow4, q4 * 32 + j * 8) = a[j];
  }
  {
    const int m = (ccnt[0] < 256) ? ccnt[0] : 256;
    if (tid < m) idxC[0][tid] = idxs[idx_base(0) + cbase[0] + tid];
  }

  const int srowB = tid >> 1, shalf = tid & 1;   // B staging coords

  // ---------- ctr GEMM ----------
  {
    const u16* W = Wt + (size_t)(2 + li) * 16384;
    uint4 pb0, pb1;
    {
      const u16* ws = W + (size_t)srowB * 128 + shalf * 16;
      pb0 = *(const uint4*)ws; pb1 = *(const uint4*)(ws + 8);
    }
    __syncthreads();   // A tile + metadata ready
    #pragma unroll
    for (int kt = 0; kt < 4; ++kt) {
      *(uint4*)swzB(srowB, shalf * 16) = pb0;
      *(uint4*)swzB(srowB, shalf * 16 + 8) = pb1;
      if (kt < 3) {
        const u16* ws = W + (size_t)srowB * 128 + (kt + 1) * 32 + shalf * 16;
        pb0 = *(const uint4*)ws; pb1 = *(const uint4*)(ws + 8);
      }
      __syncthreads();
      fragAB af[2], bf[4];
      #pragma unroll
      for (int t = 0; t < 2; t++) af[t] = *(const fragAB*)swzA(wm + t * 16 + l16, kt * 32 + q * 8);
      #pragma unroll
      for (int t = 0; t < 4; t++) bf[t] = *(const fragAB*)swzB(wn + t * 16 + l16, q * 8);
      #pragma unroll
      for (int mt = 0; mt < 2; mt++)
        #pragma unroll
        for (int nt = 0; nt < 4; nt++)
          acc[mt][nt] = __builtin_amdgcn_mfma_f32_16x16x32_bf16(af[mt], bf[nt], acc[mt][nt], 0, 0, 0);
      __syncthreads();
    }
  }

  // ---------- 14 aggregated classes ----------
  #pragma unroll 1
  for (int c = 0; c < NCLS; ++c) {
    const u16* W = Wt + (size_t)wslot(li, c) * 16384;
    const int cur = c & 1;
    if (c + 1 < NCLS) {
      const int m = (ccnt[c + 1] < 256) ? ccnt[c + 1] : 256;
      if (tid < m) idxC[cur ^ 1][tid] = idxs[idx_base(c + 1) + cbase[c + 1] + tid];
    }
    const int* icg = idxs + idx_base(c) + cbase[c];

    // gather: 2 row-groups of 32 (8 lanes/row, 16ch/lane, 2-edge ILP)
    #pragma unroll 1
    for (int grp = 0; grp < 2; ++grp) {
      const int lrow = grp * 32 + row8;
      const int lo = lrow ? (int)ends[c][lrow - 1] : 0;
      const int hi = (int)ends[c][lrow];
      float s[16];
      #pragma unroll
      for (int j = 0; j < 16; j++) s[j] = 0.f;
      int p = lo;
      #pragma unroll 1
      for (; p + 2 <= hi; p += 2) {
        const int s0 = (p     < 256) ? idxC[cur][p]     : icg[p];
        const int s1 = (p + 1 < 256) ? idxC[cur][p + 1] : icg[p + 1];
        const u16* sp0 = Fin + (size_t)s0 * 128 + goff;
        const u16* sp1 = Fin + (size_t)s1 * 128 + goff;
        uint4 a0 = ((const uint4*)sp0)[0], a1 = ((const uint4*)sp0)[1];
        uint4 b0 = ((const uint4*)sp1)[0], b1 = ((const uint4*)sp1)[1];
        acc16(s, a0, a1);
        acc16(s, b0, b1);
      }
      if (p < hi) {
        const int s0 = (p < 256) ? idxC[cur][p] : icg[p];
        const u16* sp = Fin + (size_t)s0 * 128 + goff;
        acc16(s, ((const uint4*)sp)[0], ((const uint4*)sp)[1]);
      }
      u32 pk[8];
      #pragma unroll
      for (int j = 0; j < 8; j++) pk[j] = pk2(s[2 * j], s[2 * j + 1]);
      *(uint4*)swzA(lrow, goff)     = make_uint4(pk[0], pk[1], pk[2], pk[3]);
      *(uint4*)swzA(lrow, goff + 8) = make_uint4(pk[4], pk[5], pk[6], pk[7]);
    }

    uint4 pb0, pb1;
    {
      const u16* ws = W + (size_t)srowB * 128 + shalf * 16;
      pb0 = *(const uint4*)ws; pb1 = *(const uint4*)(ws + 8);
    }
    __syncthreads();   // A tile ready

    #pragma unroll
    for (int kt = 0; kt < 4; ++kt) {
      *(uint4*)swzB(srowB, shalf * 16) = pb0;
      *(uint4*)swzB(srowB, shalf * 16 + 8) = pb1;
      if (kt < 3) {
        const u16* ws = W + (size_t)srowB * 128 + (kt + 1) * 32 + shalf * 16;
        pb0 = *(const uint4*)ws; pb1 = *(const uint4*)(ws + 8);
      }
      __syncthreads();
      fragAB af[2], bf[4];
      #pragma unroll
      for (int t = 0; t < 2; t++) af[t] = *(const fragAB*)swzA(wm + t * 16 + l16, kt * 32 + q * 8);
      #pragma unroll
      for (int t = 0; t < 4; t++) bf[t] = *(const fragAB*)swzB(wn + t * 16 + l16, q * 8);
      #pragma unroll
      for (int mt = 0; mt < 2; mt++)
        #pragma unroll
        for (int nt = 0; nt < 4; nt++)
          acc[mt][nt] = __builtin_amdgcn_mfma_f32_16x16x32_bf16(af[mt], bf[nt], acc[mt][nt], 0, 0, 0);
      __syncthreads();
    }
  }

  // ---------- GN1 + relu -> feat_mid (swizzled ldsA) ----------
  #pragma unroll
  for (int mt = 0; mt < 2; mt++)
    #pragma unroll
    for (int r = 0; r < 4; r++) {
      float s1 = acc[mt][0][r] + acc[mt][1][r] + acc[mt][2][r] + acc[mt][3][r];
      float s2 = acc[mt][0][r] * acc[mt][0][r] + acc[mt][1][r] * acc[mt][1][r]
               + acc[mt][2][r] * acc[mt][2][r] + acc[mt][3][r] * acc[mt][3][r];
      #pragma unroll
      for (int off = 1; off < 16; off <<= 1) {
        s1 += __shfl_xor(s1, off, 64);
        s2 += __shfl_xor(s2, off, 64);
      }
      if (l16 == 0) red[(wm + mt * 16 + q * 4 + r) * 2 + (wid & 1)] = make_float2(s1, s2);
    }
  __syncthreads();
  if (tid < MROWS) {
    const float2 p0 = red[tid * 2], p1 = red[tid * 2 + 1];
    const float m = (p0.x + p1.x) * (1.0f / 128.0f);
    const float var = (p0.y + p1.y) * (1.0f / 128.0f) - m * m;
    stats[tid] = make_float2(m, rsqrtf(var + 1e-5f));
  }
  __syncthreads();
  {
    float gl[4], bl[4];
    #pragma unroll
    for (int nt = 0; nt < 4; nt++) {
      gl[nt] = g1[wn + nt * 16 + l16];
      bl[nt] = b1[wn + nt * 16 + l16];
    }
    #pragma unroll
    for (int mt = 0; mt < 2; mt++)
      #pragma unroll
      for (int r = 0; r < 4; r++) {
        const int rl = wm + mt * 16 + q * 4 + r;
        const float2 st = stats[rl];
        #pragma unroll
        for (int nt = 0; nt < 4; nt++) {
          const int col = wn + nt * 16 + l16;
          const float v = fmaxf(0.f, (acc[mt][nt][r] - st.x) * st.y * gl[nt] + bl[nt]);
          *swzA(rl, col) = f2bf(v);
        }
      }
  }

  // ---------- GEMM2: feat_mid @ ctr2 ----------
  #pragma unroll
  for (int i = 0; i < 2; i++)
    #pragma unroll
    for (int j = 0; j < 4; j++)
      #pragma unroll
      for (int e = 0; e < 4; e++) acc[i][j][e] = 0.0f;
  {
    const u16* W2 = Wt + (size_t)(6 + li) * 16384;
    uint4 pb0, pb1;
    {
      const u16* ws = W2 + (size_t)srowB * 128 + shalf * 16;
      pb0 = *(const uint4*)ws; pb1 = *(const uint4*)(ws + 8);
    }
    __syncthreads();   // stats reads done (Bs alias) + feat_mid ready
    #pragma unroll
    for (int kt = 0; kt < 4; ++kt) {
      *(uint4*)swzB(srowB, shalf * 16) = pb0;
      *(uint4*)swzB(srowB, shalf * 16 + 8) = pb1;
      if (kt < 3) {
        const u16* ws = W2 + (size_t)srowB * 128 + (kt + 1) * 32 + shalf * 16;
        pb0 = *(const uint4*)ws; pb1 = *(const uint4*)(ws + 8);
      }
      __syncthreads();
      fragAB af[2], bf[4];
      #pragma unroll
      for (int t = 0; t < 2; t++) af[t] = *(const fragAB*)swzA(wm + t * 16 + l16, kt * 32 + q * 8);
      #pragma unroll
      for (int t = 0; t < 4; t++) bf[t] = *(const fragAB*)swzB(wn + t * 16 + l16, q * 8);
      #pragma unroll
      for (int mt = 0; mt < 2; mt++)
        #pragma unroll
        for (int nt = 0; nt < 4; nt++)
          acc[mt][nt] = __builtin_amdgcn_mfma_f32_16x16x32_bf16(af[mt], bf[nt], acc[mt][nt], 0, 0, 0);
      __syncthreads();
    }
  }

  // ---------- GN2 + residual(bf16) + relu + store ----------
  #pragma unroll
  for (int mt = 0; mt < 2; mt++)
    #pragma unroll
    for (int r = 0; r < 4; r++) {
      float s1 = acc[mt][0][r] + acc[mt][1][r] + acc[mt][2][r] + acc[mt][3][r];
      float s2 = acc[mt][0][r] * acc[mt][0][r] + acc[mt][1][r] * acc[mt][1][r]
               + acc[mt][2][r] * acc[mt][2][r] + acc[mt][3][r] * acc[mt][3][r];
      #pragma unroll
      for (int off = 1; off < 16; off <<= 1) {
        s1 += __shfl_xor(s1, off, 64);
        s2 += __shfl_xor(s2, off, 64);
      }
      if (l16 == 0) red[(wm + mt * 16 + q * 4 + r) * 2 + (wid & 1)] = make_float2(s1, s2);
    }
  __syncthreads();
  if (tid < MROWS) {
    const float2 p0 = red[tid * 2], p1 = red[tid * 2 + 1];
    const float m = (p0.x + p1.x) * (1.0f / 128.0f);
    const float var = (p0.y + p1.y) * (1.0f / 128.0f) - m * m;
    stats[tid] = make_float2(m, rsqrtf(var + 1e-5f));
  }
  __syncthreads();
  {
    float gl[4], bl[4];
    #pragma unroll
    for (int nt = 0; nt < 4; nt++) {
      gl[nt] = g2[wn + nt * 16 + l16];
      bl[nt] = b2[wn + nt * 16 + l16];
    }
    #pragma unroll
    for (int mt = 0; mt < 2; mt++)
      #pragma unroll
      for (int r = 0; r < 4; r++) {
        const int rl = wm + mt * 16 + q * 4 + r;
        const int grow = row0 + rl;
        if (grow >= N_NODES) continue;
        const float2 st = stats[rl];
        #pragma unroll
        for (int nt = 0; nt < 4; nt++) {
          const int col = wn + nt * 16 + l16;
          const float res = bflo((u32)Fin[(size_t)grow * 128 + col]);
          float v = (acc[mt][nt][r] - st.x) * st.y * gl[nt] + bl[nt] + res;
          v = fmaxf(v, 0.f);
          if (outf) outf[(size_t)grow * 128 + col] = v;
          else      Fout[(size_t)grow * 128 + col] = f2bf(v);
        }
      }
  }
}

// ============ weight prep: fp32 [K,128] -> bf16 transposed [128,Kp] ============
__global__ __launch_bounds__(256)
void prep_k(const float* __restrict__ in2, const float* __restrict__ seg2,
            const float* __restrict__ ctr, const float* __restrict__ ctr2,
            const float* __restrict__ lw, const float* __restrict__ rw,
            const float* __restrict__ pw, const float* __restrict__ sw,
            const float* __restrict__ meta, u16* __restrict__ Wt)
{
  const int id = blockIdx.x;
  const float* src;
  int K = 128, Kp = 128;
  if (id == 0) src = in2;
  else if (id == 1) src = seg2;
  else if (id < 6)  src = ctr  + (size_t)(id - 2) * 16384;
  else if (id < 10) src = ctr2 + (size_t)(id - 6) * 16384;
  else if (id < 14) src = lw   + (size_t)(id - 10) * 16384;
  else if (id < 18) src = rw   + (size_t)(id - 14) * 16384;
  else if (id < 42) src = pw   + (size_t)(id - 18) * 16384;
  else if (id < 66) src = sw   + (size_t)(id - 42) * 16384;
  else { src = meta; K = 132; Kp = 160; }
  u16* dst = Wt + (size_t)id * 16384;
  const int tot = 128 * Kp;
  for (int e = threadIdx.x; e < tot; e += 256) {
    const int n = e & 127, k = e >> 7;
    const float v = (k < K) ? src[(size_t)k * 128 + n] : 0.f;
    dst[(size_t)n * Kp + k] = f2bf(v);
  }
}

// ============ CSR build ============
struct EdgeCfg { const int* dst[NCLS]; const int* src[NCLS]; int cnt[NCLS]; };

__global__ __launch_bounds__(256)
void hist_k(EdgeCfg cfg, int* __restrict__ ptrs)
{
  const int c = blockIdx.y;
  const int i = blockIdx.x * 256 + threadIdx.x;
  if (i < cfg.cnt[c]) atomicAdd(ptrs + (size_t)c * (N_NODES + 1) + cfg.dst[c][i], 1);
}

__global__ __launch_bounds__(256)
void scan1_k(const int* __restrict__ ptrs, int* __restrict__ part)
{
  const int c = blockIdx.y, b = blockIdx.x;
  const int* d = ptrs + (size_t)c * (N_NODES + 1) + b * 1024;
  const int rem = min(1024, N_NODES - b * 1024);
  int s = 0;
  for (int j = threadIdx.x; j < rem; j += 256) s += d[j];
  #pragma unroll
  for (int off = 32; off; off >>= 1) s += __shfl_xor(s, off, 64);
  __shared__ int r[4];
  if ((threadIdx.x & 63) == 0) r[threadIdx.x >> 6] = s;
  __syncthreads();
  if (threadIdx.x == 0) part[c * NCHUNK + b] = r[0] + r[1] + r[2] + r[3];
}

__global__ __launch_bounds__(64)
void scan2_k(int* __restrict__ part, int* __restrict__ ptrs)
{
  const int c = blockIdx.x;
  if (threadIdx.x) return;
  int* p = part + c * NCHUNK;
  int run = 0;
  for (int b = 0; b < NCHUNK; b++) { const int t = p[b]; p[b] = run; run += t; }
  ptrs[(size_t)c * (N_NODES + 1) + N_NODES] = run;
}

__global__ __launch_bounds__(256)
void scan3_k(int* __restrict__ ptrs, const int* __restrict__ part)
{
  const int c = blockIdx.y, b = blockIdx.x;
  int* d = ptrs + (size_t)c * (N_NODES + 1) + b * 1024;
  const int base = part[c * NCHUNK + b];
  const int gbase = b * 1024;
  const int i0 = threadIdx.x * 4;
  int v[4];
  #pragma unroll
  for (int j = 0; j < 4; j++) v[j] = (gbase + i0 + j < N_NODES) ? d[i0 + j] : 0;
  const int tsum = v[0] + v[1] + v[2] + v[3];
  __shared__ int sc[256];
  sc[threadIdx.x] = tsum;
  __syncthreads();
  #pragma unroll
  for (int off = 1; off < 256; off <<= 1) {
    const int t = (threadIdx.x >= off) ? sc[threadIdx.x - off] : 0;
    __syncthreads();
    sc[threadIdx.x] += t;
    __syncthreads();
  }
  int run = sc[threadIdx.x] - tsum + base;
  #pragma unroll
  for (int j = 0; j < 4; j++) {
    if (gbase + i0 + j < N_NODES) d[i0 + j] = run;
    run += v[j];
  }
}

// fill stores SOURCE node ids; ptrs become end-offsets
__global__ __launch_bounds__(256)
void fill_k(EdgeCfg cfg, int* __restrict__ ptrs, int* __restrict__ idxs)
{
  const int c = blockIdx.y;
  const int i = blockIdx.x * 256 + threadIdx.x;
  if (i >= cfg.cnt[c]) return;
  const int d = cfg.dst[c][i];
  const int slot = atomicAdd(ptrs + (size_t)c * (N_NODES + 1) + d, 1);
  idxs[idx_base(c) + slot] = cfg.src[c][i];
}

__global__ __launch_bounds__(256)
void copy_k(const float* __restrict__ src, float* __restrict__ dst, int n)
{
  const int i = blockIdx.x * 256 + threadIdx.x;
  if (i < n) dst[i] = src[i];
}

extern "C" void kernel_launch(void* const* d_in, const int* in_sizes, int n_in,
                              void* d_out, int out_size, void* d_ws, size_t ws_size,
                              hipStream_t stream) {
  const float* control   = (const float*)d_in[0];
  const float* turn      = (const float*)d_in[1];
  const float* intersect = (const float*)d_in[2];
  const float* ctrs      = (const float*)d_in[3];
  const float* feats     = (const float*)d_in[4];
  const int*   pre   = (const int*)d_in[5];
  const int*   suc   = (const int*)d_in[6];
  const int*   left  = (const int*)d_in[7];
  const int*   right = (const int*)d_in[8];
  const float* w_in1   = (const float*)d_in[9];
  const float* b_in1   = (const float*)d_in[10];
  const float* w_in2   = (const float*)d_in[11];
  const float* gn_in_g = (const float*)d_in[12];
  const float* gn_in_b = (const float*)d_in[13];
  const float* w_seg1   = (const float*)d_in[14];
  const float* b_seg1   = (const float*)d_in[15];
  const float* w_seg2   = (const float*)d_in[16];
  const float* gn_seg_g = (const float*)d_in[17];
  const float* gn_seg_b = (const float*)d_in[18];
  const float* w_meta    = (const float*)d_in[19];
  const float* gn_meta_g = (const float*)d_in[20];
  const float* gn_meta_b = (const float*)d_in[21];
  const float* ctr_w   = (const float*)d_in[22];
  const float* pre_w   = (const float*)d_in[23];
  const float* suc_w   = (const float*)d_in[24];
  const float* left_w  = (const float*)d_in[25];
  const float* right_w = (const float*)d_in[26];
  const float* norm_g  = (const float*)d_in[27];
  const float* norm_b  = (const float*)d_in[28];
  const float* ctr2_w  = (const float*)d_in[29];
  const float* ctr2_g  = (const float*)d_in[30];
  const float* ctr2_b  = (const float*)d_in[31];

  const size_t NF = (size_t)N_NODES * CDIM;
  char* w = (char*)d_ws;
  float* Ta = (float*)w;  w += NF * 4;           // a-branch
  float* Tb = (float*)w;  w += NF * 4;           // b-branch
  u16* Fb0  = (u16*)w;    w += NF * 2;
  u16* Fb1  = (u16*)w;    w += NF * 2;
  u16* Wt   = (u16*)w;    w += (size_t)(67 * 16384 + 128 * 160) * 2;
  int* ptrs = (int*)w;    w += (size_t)NCLS * (N_NODES + 1) * 4;
  int* idxs = (int*)w;    w += (size_t)(12 * NEP + 2 * NEL) * 4;
  int* part = (int*)w;
  float* out = (float*)d_out;

  EdgeCfg cfg;
  for (int s = 0; s < NSCALE; s++) {
    cfg.dst[s] = pre + (size_t)s * 2 * NEP;     cfg.src[s] = pre + ((size_t)s * 2 + 1) * NEP;     cfg.cnt[s] = NEP;
    cfg.dst[6 + s] = suc + (size_t)s * 2 * NEP; cfg.src[6 + s] = suc + ((size_t)s * 2 + 1) * NEP; cfg.cnt[6 + s] = NEP;
  }
  cfg.dst[12] = left;  cfg.src[12] = left + NEL;  cfg.cnt[12] = NEL;
  cfg.dst[13] = right; cfg.src[13] = right + NEL; cfg.cnt[13] = NEL;

  const dim3 blk(256);
  const dim3 gN((N_NODES + 127) / 128);   // 1563 (prologue)
  const dim3 gL((N_NODES + MROWS - 1) / MROWS);   // 3125 (layers)
  const dim3 gHist((NEP + 255) / 256, NCLS);
  const dim3 gScan(NCHUNK, NCLS);

  // ---- weight prep + CSR build ----
  prep_k<<<dim3(67), blk, 0, stream>>>(w_in2, w_seg2, ctr_w, ctr2_w, left_w, right_w,
                                       pre_w, suc_w, w_meta, Wt);
  (void)hipMemsetAsync(ptrs, 0, (size_t)NCLS * (N_NODES + 1) * sizeof(int), stream);
  hist_k<<<gHist, blk, 0, stream>>>(cfg, ptrs);
  scan1_k<<<gScan, blk, 0, stream>>>(ptrs, part);
  scan2_k<<<dim3(NCLS), dim3(64), 0, stream>>>(part, ptrs);
  scan3_k<<<gScan, blk, 0, stream>>>(ptrs, part);
  fill_k<<<gHist, blk, 0, stream>>>(cfg, ptrs, idxs);

  // ---- prologue: a-branch -> Ta, b-branch -> Tb, meta -> Fb0 (bf16 only) ----
  mm_k<P_TWO, E_GN><<<gN, blk, 0, stream>>>(N_NODES, 128, ctrs, nullptr,
      w_in1, b_in1, nullptr, Wt + 0 * 16384, Ta, nullptr, gn_in_g, gn_in_b);
  mm_k<P_TWO, E_GN><<<gN, blk, 0, stream>>>(N_NODES, 128, feats, nullptr,
      w_seg1, b_seg1, nullptr, Wt + 1 * 16384, Tb, nullptr, gn_seg_g, gn_seg_b);
  mm_k<P_META, E_GN | E_RELU><<<gN, blk, 0, stream>>>(N_NODES, 160, Ta, Tb,
      turn, control, intersect, Wt + 66 * 16384, nullptr, Fb0, gn_meta_g, gn_meta_b);

  // ---- 4 fused layers (double-buffered bf16 features) ----
  for (int i = 0; i < 4; i++) {
    const u16* Fin = (i & 1) ? Fb1 : Fb0;
    u16* Fout      = (i & 1) ? Fb0 : Fb1;
    layer_k<<<gL, blk, 0, stream>>>(Fin, Fout, (i == 3) ? out : nullptr,
        ptrs, idxs, Wt, i,
        norm_g + i * 128, norm_b + i * 128, ctr2_g + i * 128, ctr2_b + i * 128);
  }

  copy_k<<<dim3((2 * N_NODES + 255) / 256), blk, 0, stream>>>(ctrs, out + NF, 2 * N_NODES);
}

// Round 12
// 1712.073 us; speedup vs baseline: 1.1970x; 1.1970x over previous
//
#include <hip/hip_runtime.h>

#define N_NODES 200000
#define CDIM 128
#define NSCALE 6
#define NEP 100000
#define NEL 25000
#define NCLS 14
#define NCHUNK 196   // ceil(200000/1024)
#define MROWS 64     // layer_k tile rows

typedef unsigned short u16;
typedef unsigned int u32;

using fragAB = __attribute__((ext_vector_type(8))) short;  // 8 bf16
using fragC  = __attribute__((ext_vector_type(4))) float;  // 4 fp32

enum { P_PLAIN = 0, P_TWO = 1, P_META = 2 };
enum { E_GN = 1, E_RELU = 2 };

__device__ __forceinline__ float4 ld4(const float* p) { return *(const float4*)p; }

__device__ __forceinline__ u16 f2bf(float f) {
  u32 u = __builtin_bit_cast(u32, f);
  u = (u + 0x7fff + ((u >> 16) & 1)) >> 16;
  return (u16)u;
}
__device__ __forceinline__ u32 pk2(float a, float b) {
  return (u32)f2bf(a) | ((u32)f2bf(b) << 16);
}
__device__ __forceinline__ float bflo(u32 u) { return __builtin_bit_cast(float, u << 16); }
__device__ __forceinline__ float bfhi(u32 u) { return __builtin_bit_cast(float, u & 0xffff0000u); }

__device__ __forceinline__ void acc16(float* s, uint4 a, uint4 b) {
  s[0] += bflo(a.x); s[1] += bfhi(a.x); s[2]  += bflo(a.y); s[3]  += bfhi(a.y);
  s[4] += bflo(a.z); s[5] += bfhi(a.z); s[6]  += bflo(a.w); s[7]  += bfhi(a.w);
  s[8] += bflo(b.x); s[9] += bfhi(b.x); s[10] += bflo(b.y); s[11] += bfhi(b.y);
  s[12] += bflo(b.z); s[13] += bfhi(b.z); s[14] += bflo(b.w); s[15] += bfhi(b.w);
}

__host__ __device__ constexpr int idx_base(int c) {
  return (c < 12) ? c * NEP : 12 * NEP + (c - 12) * NEL;
}

// weight slot table (prep_k layout): 0 in2, 1 seg2, 2-5 ctr, 6-9 ctr2, 10-13 left,
// 14-17 right, 18-41 pre[i*6+s], 42-65 suc[i*6+s], 66 meta
__device__ __forceinline__ int wslot(int li, int c) {
  if (c < 0)  return 2 + li;
  if (c < 6)  return 18 + li * 6 + c;
  if (c < 12) return 42 + li * 6 + (c - 6);
  return (c == 12) ? (10 + li) : (14 + li);
}

// ================= prologue MFMA GEMM (a/b/meta branches) =================
template<int PRO, int EPI>
__global__ __launch_bounds__(256)
void mm_k(int M, int Kp,
          const float* __restrict__ Af, const float* __restrict__ A2f,
          const float* __restrict__ e0, const float* __restrict__ e1, const float* __restrict__ e2,
          const u16* __restrict__ Wt,
          float* __restrict__ Y, u16* __restrict__ Yb,
          const float* __restrict__ gn_g, const float* __restrict__ gn_b)
{
  constexpr int LSTR = 56;
  __shared__ u16 As[128 * LSTR];
  __shared__ u16 Bs[128 * LSTR];

  const int tid = threadIdx.x;
  const int lane = tid & 63, wid = tid >> 6;
  const int wm = (wid >> 1) * 64, wn = (wid & 1) * 64;
  const int q = lane >> 4, l16 = lane & 15;
  const int row0 = blockIdx.x * 128;
  const int srow = tid >> 1, shalf = tid & 1;

  fragC acc[4][4];
  #pragma unroll
  for (int i = 0; i < 4; i++)
    #pragma unroll
    for (int j = 0; j < 4; j++)
      #pragma unroll
      for (int e = 0; e < 4; e++) acc[i][j][e] = 0.0f;

  const int sgrow = row0 + srow;
  const bool svalid = (sgrow < M);
  float x0 = 0.f, x1 = 0.f, mx = 0.f, my = 0.f, mc = 0.f, mi = 0.f;
  if constexpr (PRO == P_TWO) {
    if (svalid) { x0 = Af[(size_t)sgrow * 2]; x1 = Af[(size_t)sgrow * 2 + 1]; }
  }
  if constexpr (PRO == P_META) {
    if (svalid) { mx = e0[(size_t)sgrow * 2]; my = e0[(size_t)sgrow * 2 + 1]; mc = e1[sgrow]; mi = e2[sgrow]; }
  }

  const int nk = Kp >> 5;
  for (int kt = 0; kt < nk; ++kt) {
    const int k0 = kt * 32 + shalf * 16;
    {
      u16* adst = &As[srow * LSTR + shalf * 16];
      float v[16];
      #pragma unroll
      for (int j = 0; j < 16; j++) v[j] = 0.f;
      if constexpr (PRO == P_TWO) {
        #pragma unroll
        for (int j0 = 0; j0 < 16; j0 += 4) {
          float4 wa = ld4(e0 + k0 + j0);
          float4 wb = ld4(e0 + 128 + k0 + j0);
          float4 bb = ld4(e1 + k0 + j0);
          v[j0]     = fmaxf(0.f, fmaf(x0, wa.x, fmaf(x1, wb.x, bb.x)));
          v[j0 + 1] = fmaxf(0.f, fmaf(x0, wa.y, fmaf(x1, wb.y, bb.y)));
          v[j0 + 2] = fmaxf(0.f, fmaf(x0, wa.z, fmaf(x1, wb.z, bb.z)));
          v[j0 + 3] = fmaxf(0.f, fmaf(x0, wa.w, fmaf(x1, wb.w, bb.w)));
        }
      } else { // P_META
        if (svalid) {
          if (k0 < 128) {
            const float* sa = Af + (size_t)sgrow * 128 + k0;
            const float* sb = A2f + (size_t)sgrow * 128 + k0;
            #pragma unroll
            for (int j0 = 0; j0 < 16; j0 += 4) {
              float4 a = ld4(sa + j0), b = ld4(sb + j0);
              v[j0]     = fmaxf(0.f, a.x + b.x);
              v[j0 + 1] = fmaxf(0.f, a.y + b.y);
              v[j0 + 2] = fmaxf(0.f, a.z + b.z);
              v[j0 + 3] = fmaxf(0.f, a.w + b.w);
            }
          } else {
            #pragma unroll
            for (int j = 0; j < 16; j++) {
              const int kk = k0 + j - 128;
              v[j] = (kk == 0) ? mx : (kk == 1) ? my : (kk == 2) ? mc : (kk == 3) ? mi : 0.f;
            }
          }
        }
      }
      u32 p[8];
      #pragma unroll
      for (int j = 0; j < 8; j++) p[j] = pk2(v[2 * j], v[2 * j + 1]);
      *(uint4*)adst = make_uint4(p[0], p[1], p[2], p[3]);
      *(uint4*)(adst + 8) = make_uint4(p[4], p[5], p[6], p[7]);
    }
    {
      const u16* s = Wt + (size_t)srow * Kp + k0;
      uint4 b0 = *(const uint4*)s, b1 = *(const uint4*)(s + 8);
      u16* bdst = &Bs[srow * LSTR + shalf * 16];
      *(uint4*)bdst = b0; *(uint4*)(bdst + 8) = b1;
    }
    __syncthreads();
    fragAB af[4], bf[4];
    #pragma unroll
    for (int t = 0; t < 4; t++) af[t] = *(const fragAB*)&As[(wm + t * 16 + l16) * LSTR + q * 8];
    #pragma unroll
    for (int t = 0; t < 4; t++) bf[t] = *(const fragAB*)&Bs[(wn + t * 16 + l16) * LSTR + q * 8];
    #pragma unroll
    for (int mt = 0; mt < 4; mt++)
      #pragma unroll
      for (int nt = 0; nt < 4; nt++)
        acc[mt][nt] = __builtin_amdgcn_mfma_f32_16x16x32_bf16(af[mt], bf[nt], acc[mt][nt], 0, 0, 0);
    __syncthreads();
  }

  // GN epilogue
  __shared__ float2 red[128][2];
  __shared__ float2 stats[128];
  #pragma unroll
  for (int mt = 0; mt < 4; mt++)
    #pragma unroll
    for (int r = 0; r < 4; r++) {
      float s1 = acc[mt][0][r] + acc[mt][1][r] + acc[mt][2][r] + acc[mt][3][r];
      float s2 = acc[mt][0][r] * acc[mt][0][r] + acc[mt][1][r] * acc[mt][1][r]
               + acc[mt][2][r] * acc[mt][2][r] + acc[mt][3][r] * acc[mt][3][r];
      #pragma unroll
      for (int off = 1; off < 16; off <<= 1) {
        s1 += __shfl_xor(s1, off, 64);
        s2 += __shfl_xor(s2, off, 64);
      }
      if (l16 == 0) red[wm + mt * 16 + q * 4 + r][wid & 1] = make_float2(s1, s2);
    }
  __syncthreads();
  if (tid < 128) {
    const float2 p0 = red[tid][0], p1 = red[tid][1];
    const float m = (p0.x + p1.x) * (1.0f / 128.0f);
    const float var = (p0.y + p1.y) * (1.0f / 128.0f) - m * m;
    stats[tid] = make_float2(m, rsqrtf(var + 1e-5f));
  }
  __syncthreads();
  float gl[4], bl[4];
  #pragma unroll
  for (int nt = 0; nt < 4; nt++) {
    gl[nt] = gn_g[wn + nt * 16 + l16];
    bl[nt] = gn_b[wn + nt * 16 + l16];
  }
  #pragma unroll
  for (int mt = 0; mt < 4; mt++)
    #pragma unroll
    for (int r = 0; r < 4; r++) {
      const int rl = wm + mt * 16 + q * 4 + r;
      const int grow = row0 + rl;
      if (grow >= M) continue;
      const float2 st = stats[rl];
      #pragma unroll
      for (int nt = 0; nt < 4; nt++) {
        const int col = wn + nt * 16 + l16;
        float v = (acc[mt][nt][r] - st.x) * st.y * gl[nt] + bl[nt];
        if constexpr ((EPI & E_RELU) != 0) v = fmaxf(v, 0.f);
        if (Y)  Y[(size_t)grow * 128 + col] = v;
        if (Yb) Yb[(size_t)grow * 128 + col] = f2bf(v);
      }
    }
}

// ================= fused per-layer kernel (64-row tiles) =================
// R11 geometry with the spill fixed: __launch_bounds__(256,4) caps at 128
// unified regs >= demand (~116 = 32 AGPR acc + ~84 VGPR), so the gather loop
// stays register-resident. 4 blocks/CU (16 waves) vs R10's 3 (12 waves).
// Carries over: idx-cache + ends table (1-level gather chain), T2 XOR swizzle
// on both tiles, per-kt B staging.
__global__ __launch_bounds__(256, 4)
void layer_k(const u16* __restrict__ Fin, u16* __restrict__ Fout,
             float* __restrict__ outf,
             const int* __restrict__ ptrs, const int* __restrict__ idxs,
             const u16* __restrict__ Wt, int li,
             const float* __restrict__ g1, const float* __restrict__ b1,
             const float* __restrict__ g2, const float* __restrict__ b2)
{
  __shared__ u16 ldsA[MROWS * 128];    // 16384B, swizzled A tile / feat_mid
  __shared__ u16 Bsb[128 * 32];        // 8192B, swizzled per-kt B chunk; aliases red/stats
  __shared__ u16 ends[NCLS][MROWS];    // 1792B, block-local CSR end offsets
  __shared__ int cbase[NCLS];
  __shared__ int ccnt[NCLS];
  __shared__ int idxC[2][256];         // 2048B, double-buffered edge indices

  float2* red   = (float2*)Bsb;          // [64][2], bytes 0..1023
  float2* stats = (float2*)(Bsb + 512);  // [64],   bytes 1024..1535

  const int tid = threadIdx.x;
  const int lane = tid & 63, wid = tid >> 6;
  const int wm = (wid >> 1) * 32, wn = (wid & 1) * 64;
  const int q = lane >> 4, l16 = lane & 15;
  const int row0 = blockIdx.x * MROWS;
  const int row8 = tid >> 3;          // gather: row within group (0..31)
  const int goff = (tid & 7) * 16;    // gather: channel offset (0..112)

  // XOR-swizzled tile addressing (16B granules; same XOR on every access)
  auto swzA = [&](int row, int colu) -> u16* {
    u32 b = (u32)(row * 256 + colu * 2) ^ ((u32)(row & 7) << 4);
    return (u16*)((char*)ldsA + b);
  };
  auto swzB = [&](int row, int colu) -> u16* {
    u32 b = (u32)(row * 64 + colu * 2) ^ ((((u32)((row >> 1) ^ (row >> 3))) & 3u) << 4);
    return (u16*)((char*)Bsb + b);
  };

  fragC acc[2][4];
  #pragma unroll
  for (int i = 0; i < 2; i++)
    #pragma unroll
    for (int j = 0; j < 4; j++)
      #pragma unroll
      for (int e = 0; e < 4; e++) acc[i][j][e] = 0.0f;

  // ---------- upfront: class bases ----------
  if (tid < NCLS) {
    const int* pc = ptrs + (size_t)tid * (N_NODES + 1);
    const int b = row0 ? pc[row0 - 1] : 0;
    const int hiRow = (row0 + MROWS - 1 < N_NODES) ? (row0 + MROWS - 1) : (N_NODES - 1);
    cbase[tid] = b;
    ccnt[tid] = pc[hiRow] - b;
  }
  __syncthreads();

  // ---------- upfront: ends table + ctr A stage + idx cache cls0 ----------
  #pragma unroll 1
  for (int t = tid; t < NCLS * MROWS; t += 256) {
    const int c = t / MROWS, r = t % MROWS;
    const int grow = row0 + r;
    const int* pc = ptrs + (size_t)c * (N_NODES + 1);
    const int gr = (grow < N_NODES) ? grow : (N_NODES - 1);
    ends[c][r] = (u16)(pc[gr] - cbase[c]);
  }
  {
    const int srow4 = tid >> 2, q4 = tid & 3;   // 64 rows x 4 quarters (32ch)
    const int sgrow = row0 + srow4;
    uint4 a[4];
    #pragma unroll
    for (int j = 0; j < 4; j++) a[j] = make_uint4(0, 0, 0, 0);
    if (sgrow < N_NODES) {
      const u16* s = Fin + (size_t)sgrow * 128 + q4 * 32;
      #pragma unroll
      for (int j = 0; j < 4; j++) a[j] = ((const uint4*)s)[j];
    }
    #pragma unroll
    for (int j = 0; j < 4; j++) *(uint4*)swzA(srow4, q4 * 32 + j * 8) = a[j];
  }
  {
    const int m = (ccnt[0] < 256) ? ccnt[0] : 256;
    if (tid < m) idxC[0][tid] = idxs[idx_base(0) + cbase[0] + tid];
  }

  const int srowB = tid >> 1, shalf = tid & 1;   // B staging coords

  // ---------- ctr GEMM ----------
  {
    const u16* W = Wt + (size_t)(2 + li) * 16384;
    uint4 pb0, pb1;
    {
      const u16* ws = W + (size_t)srowB * 128 + shalf * 16;
      pb0 = *(const uint4*)ws; pb1 = *(const uint4*)(ws + 8);
    }
    __syncthreads();   // A tile + metadata ready
    #pragma unroll
    for (int kt = 0; kt < 4; ++kt) {
      *(uint4*)swzB(srowB, shalf * 16) = pb0;
      *(uint4*)swzB(srowB, shalf * 16 + 8) = pb1;
      if (kt < 3) {
        const u16* ws = W + (size_t)srowB * 128 + (kt + 1) * 32 + shalf * 16;
        pb0 = *(const uint4*)ws; pb1 = *(const uint4*)(ws + 8);
      }
      __syncthreads();
      fragAB af[2], bf[4];
      #pragma unroll
      for (int t = 0; t < 2; t++) af[t] = *(const fragAB*)swzA(wm + t * 16 + l16, kt * 32 + q * 8);
      #pragma unroll
      for (int t = 0; t < 4; t++) bf[t] = *(const fragAB*)swzB(wn + t * 16 + l16, q * 8);
      #pragma unroll
      for (int mt = 0; mt < 2; mt++)
        #pragma unroll
        for (int nt = 0; nt < 4; nt++)
          acc[mt][nt] = __builtin_amdgcn_mfma_f32_16x16x32_bf16(af[mt], bf[nt], acc[mt][nt], 0, 0, 0);
      __syncthreads();
    }
  }

  // ---------- 14 aggregated classes ----------
  #pragma unroll 1
  for (int c = 0; c < NCLS; ++c) {
    const u16* W = Wt + (size_t)wslot(li, c) * 16384;
    const int cur = c & 1;
    if (c + 1 < NCLS) {
      const int m = (ccnt[c + 1] < 256) ? ccnt[c + 1] : 256;
      if (tid < m) idxC[cur ^ 1][tid] = idxs[idx_base(c + 1) + cbase[c + 1] + tid];
    }
    const int* icg = idxs + idx_base(c) + cbase[c];

    // gather: 2 row-groups of 32 (8 lanes/row, 16ch/lane, 2-edge ILP)
    #pragma unroll 1
    for (int grp = 0; grp < 2; ++grp) {
      const int lrow = grp * 32 + row8;
      const int lo = lrow ? (int)ends[c][lrow - 1] : 0;
      const int hi = (int)ends[c][lrow];
      float s[16];
      #pragma unroll
      for (int j = 0; j < 16; j++) s[j] = 0.f;
      int p = lo;
      #pragma unroll 1
      for (; p + 2 <= hi; p += 2) {
        const int s0 = (p     < 256) ? idxC[cur][p]     : icg[p];
        const int s1 = (p + 1 < 256) ? idxC[cur][p + 1] : icg[p + 1];
        const u16* sp0 = Fin + (size_t)s0 * 128 + goff;
        const u16* sp1 = Fin + (size_t)s1 * 128 + goff;
        uint4 a0 = ((const uint4*)sp0)[0], a1 = ((const uint4*)sp0)[1];
        uint4 b0 = ((const uint4*)sp1)[0], b1 = ((const uint4*)sp1)[1];
        acc16(s, a0, a1);
        acc16(s, b0, b1);
      }
      if (p < hi) {
        const int s0 = (p < 256) ? idxC[cur][p] : icg[p];
        const u16* sp = Fin + (size_t)s0 * 128 + goff;
        acc16(s, ((const uint4*)sp)[0], ((const uint4*)sp)[1]);
      }
      u32 pk[8];
      #pragma unroll
      for (int j = 0; j < 8; j++) pk[j] = pk2(s[2 * j], s[2 * j + 1]);
      *(uint4*)swzA(lrow, goff)     = make_uint4(pk[0], pk[1], pk[2], pk[3]);
      *(uint4*)swzA(lrow, goff + 8) = make_uint4(pk[4], pk[5], pk[6], pk[7]);
    }

    uint4 pb0, pb1;
    {
      const u16* ws = W + (size_t)srowB * 128 + shalf * 16;
      pb0 = *(const uint4*)ws; pb1 = *(const uint4*)(ws + 8);
    }
    __syncthreads();   // A tile ready

    #pragma unroll
    for (int kt = 0; kt < 4; ++kt) {
      *(uint4*)swzB(srowB, shalf * 16) = pb0;
      *(uint4*)swzB(srowB, shalf * 16 + 8) = pb1;
      if (kt < 3) {
        const u16* ws = W + (size_t)srowB * 128 + (kt + 1) * 32 + shalf * 16;
        pb0 = *(const uint4*)ws; pb1 = *(const uint4*)(ws + 8);
      }
      __syncthreads();
      fragAB af[2], bf[4];
      #pragma unroll
      for (int t = 0; t < 2; t++) af[t] = *(const fragAB*)swzA(wm + t * 16 + l16, kt * 32 + q * 8);
      #pragma unroll
      for (int t = 0; t < 4; t++) bf[t] = *(const fragAB*)swzB(wn + t * 16 + l16, q * 8);
      #pragma unroll
      for (int mt = 0; mt < 2; mt++)
        #pragma unroll
        for (int nt = 0; nt < 4; nt++)
          acc[mt][nt] = __builtin_amdgcn_mfma_f32_16x16x32_bf16(af[mt], bf[nt], acc[mt][nt], 0, 0, 0);
      __syncthreads();
    }
  }

  // ---------- GN1 + relu -> feat_mid (swizzled ldsA) ----------
  #pragma unroll
  for (int mt = 0; mt < 2; mt++)
    #pragma unroll
    for (int r = 0; r < 4; r++) {
      float s1 = acc[mt][0][r] + acc[mt][1][r] + acc[mt][2][r] + acc[mt][3][r];
      float s2 = acc[mt][0][r] * acc[mt][0][r] + acc[mt][1][r] * acc[mt][1][r]
               + acc[mt][2][r] * acc[mt][2][r] + acc[mt][3][r] * acc[mt][3][r];
      #pragma unroll
      for (int off = 1; off < 16; off <<= 1) {
        s1 += __shfl_xor(s1, off, 64);
        s2 += __shfl_xor(s2, off, 64);
      }
      if (l16 == 0) red[(wm + mt * 16 + q * 4 + r) * 2 + (wid & 1)] = make_float2(s1, s2);
    }
  __syncthreads();
  if (tid < MROWS) {
    const float2 p0 = red[tid * 2], p1 = red[tid * 2 + 1];
    const float m = (p0.x + p1.x) * (1.0f / 128.0f);
    const float var = (p0.y + p1.y) * (1.0f / 128.0f) - m * m;
    stats[tid] = make_float2(m, rsqrtf(var + 1e-5f));
  }
  __syncthreads();
  {
    float gl[4], bl[4];
    #pragma unroll
    for (int nt = 0; nt < 4; nt++) {
      gl[nt] = g1[wn + nt * 16 + l16];
      bl[nt] = b1[wn + nt * 16 + l16];
    }
    #pragma unroll
    for (int mt = 0; mt < 2; mt++)
      #pragma unroll
      for (int r = 0; r < 4; r++) {
        const int rl = wm + mt * 16 + q * 4 + r;
        const float2 st = stats[rl];
        #pragma unroll
        for (int nt = 0; nt < 4; nt++) {
          const int col = wn + nt * 16 + l16;
          const float v = fmaxf(0.f, (acc[mt][nt][r] - st.x) * st.y * gl[nt] + bl[nt]);
          *swzA(rl, col) = f2bf(v);
        }
      }
  }

  // ---------- GEMM2: feat_mid @ ctr2 ----------
  #pragma unroll
  for (int i = 0; i < 2; i++)
    #pragma unroll
    for (int j = 0; j < 4; j++)
      #pragma unroll
      for (int e = 0; e < 4; e++) acc[i][j][e] = 0.0f;
  {
    const u16* W2 = Wt + (size_t)(6 + li) * 16384;
    uint4 pb0, pb1;
    {
      const u16* ws = W2 + (size_t)srowB * 128 + shalf * 16;
      pb0 = *(const uint4*)ws; pb1 = *(const uint4*)(ws + 8);
    }
    __syncthreads();   // stats reads done (Bs alias) + feat_mid ready
    #pragma unroll
    for (int kt = 0; kt < 4; ++kt) {
      *(uint4*)swzB(srowB, shalf * 16) = pb0;
      *(uint4*)swzB(srowB, shalf * 16 + 8) = pb1;
      if (kt < 3) {
        const u16* ws = W2 + (size_t)srowB * 128 + (kt + 1) * 32 + shalf * 16;
        pb0 = *(const uint4*)ws; pb1 = *(const uint4*)(ws + 8);
      }
      __syncthreads();
      fragAB af[2], bf[4];
      #pragma unroll
      for (int t = 0; t < 2; t++) af[t] = *(const fragAB*)swzA(wm + t * 16 + l16, kt * 32 + q * 8);
      #pragma unroll
      for (int t = 0; t < 4; t++) bf[t] = *(const fragAB*)swzB(wn + t * 16 + l16, q * 8);
      #pragma unroll
      for (int mt = 0; mt < 2; mt++)
        #pragma unroll
        for (int nt = 0; nt < 4; nt++)
          acc[mt][nt] = __builtin_amdgcn_mfma_f32_16x16x32_bf16(af[mt], bf[nt], acc[mt][nt], 0, 0, 0);
      __syncthreads();
    }
  }

  // ---------- GN2 + residual(bf16) + relu + store ----------
  #pragma unroll
  for (int mt = 0; mt < 2; mt++)
    #pragma unroll
    for (int r = 0; r < 4; r++) {
      float s1 = acc[mt][0][r] + acc[mt][1][r] + acc[mt][2][r] + acc[mt][3][r];
      float s2 = acc[mt][0][r] * acc[mt][0][r] + acc[mt][1][r] * acc[mt][1][r]
               + acc[mt][2][r] * acc[mt][2][r] + acc[mt][3][r] * acc[mt][3][r];
      #pragma unroll
      for (int off = 1; off < 16; off <<= 1) {
        s1 += __shfl_xor(s1, off, 64);
        s2 += __shfl_xor(s2, off, 64);
      }
      if (l16 == 0) red[(wm + mt * 16 + q * 4 + r) * 2 + (wid & 1)] = make_float2(s1, s2);
    }
  __syncthreads();
  if (tid < MROWS) {
    const float2 p0 = red[tid * 2], p1 = red[tid * 2 + 1];
    const float m = (p0.x + p1.x) * (1.0f / 128.0f);
    const float var = (p0.y + p1.y) * (1.0f / 128.0f) - m * m;
    stats[tid] = make_float2(m, rsqrtf(var + 1e-5f));
  }
  __syncthreads();
  {
    float gl[4], bl[4];
    #pragma unroll
    for (int nt = 0; nt < 4; nt++) {
      gl[nt] = g2[wn + nt * 16 + l16];
      bl[nt] = b2[wn + nt * 16 + l16];
    }
    #pragma unroll
    for (int mt = 0; mt < 2; mt++)
      #pragma unroll
      for (int r = 0; r < 4; r++) {
        const int rl = wm + mt * 16 + q * 4 + r;
        const int grow = row0 + rl;
        if (grow >= N_NODES) continue;
        const float2 st = stats[rl];
        #pragma unroll
        for (int nt = 0; nt < 4; nt++) {
          const int col = wn + nt * 16 + l16;
          const float res = bflo((u32)Fin[(size_t)grow * 128 + col]);
          float v = (acc[mt][nt][r] - st.x) * st.y * gl[nt] + bl[nt] + res;
          v = fmaxf(v, 0.f);
          if (outf) outf[(size_t)grow * 128 + col] = v;
          else      Fout[(size_t)grow * 128 + col] = f2bf(v);
        }
      }
  }
}

// ============ weight prep: fp32 [K,128] -> bf16 transposed [128,Kp] ============
__global__ __launch_bounds__(256)
void prep_k(const float* __restrict__ in2, const float* __restrict__ seg2,
            const float* __restrict__ ctr, const float* __restrict__ ctr2,
            const float* __restrict__ lw, const float* __restrict__ rw,
            const float* __restrict__ pw, const float* __restrict__ sw,
            const float* __restrict__ meta, u16* __restrict__ Wt)
{
  const int id = blockIdx.x;
  const float* src;
  int K = 128, Kp = 128;
  if (id == 0) src = in2;
  else if (id == 1) src = seg2;
  else if (id < 6)  src = ctr  + (size_t)(id - 2) * 16384;
  else if (id < 10) src = ctr2 + (size_t)(id - 6) * 16384;
  else if (id < 14) src = lw   + (size_t)(id - 10) * 16384;
  else if (id < 18) src = rw   + (size_t)(id - 14) * 16384;
  else if (id < 42) src = pw   + (size_t)(id - 18) * 16384;
  else if (id < 66) src = sw   + (size_t)(id - 42) * 16384;
  else { src = meta; K = 132; Kp = 160; }
  u16* dst = Wt + (size_t)id * 16384;
  const int tot = 128 * Kp;
  for (int e = threadIdx.x; e < tot; e += 256) {
    const int n = e & 127, k = e >> 7;
    const float v = (k < K) ? src[(size_t)k * 128 + n] : 0.f;
    dst[(size_t)n * Kp + k] = f2bf(v);
  }
}

// ============ CSR build ============
struct EdgeCfg { const int* dst[NCLS]; const int* src[NCLS]; int cnt[NCLS]; };

__global__ __launch_bounds__(256)
void hist_k(EdgeCfg cfg, int* __restrict__ ptrs)
{
  const int c = blockIdx.y;
  const int i = blockIdx.x * 256 + threadIdx.x;
  if (i < cfg.cnt[c]) atomicAdd(ptrs + (size_t)c * (N_NODES + 1) + cfg.dst[c][i], 1);
}

__global__ __launch_bounds__(256)
void scan1_k(const int* __restrict__ ptrs, int* __restrict__ part)
{
  const int c = blockIdx.y, b = blockIdx.x;
  const int* d = ptrs + (size_t)c * (N_NODES + 1) + b * 1024;
  const int rem = min(1024, N_NODES - b * 1024);
  int s = 0;
  for (int j = threadIdx.x; j < rem; j += 256) s += d[j];
  #pragma unroll
  for (int off = 32; off; off >>= 1) s += __shfl_xor(s, off, 64);
  __shared__ int r[4];
  if ((threadIdx.x & 63) == 0) r[threadIdx.x >> 6] = s;
  __syncthreads();
  if (threadIdx.x == 0) part[c * NCHUNK + b] = r[0] + r[1] + r[2] + r[3];
}

__global__ __launch_bounds__(64)
void scan2_k(int* __restrict__ part, int* __restrict__ ptrs)
{
  const int c = blockIdx.x;
  if (threadIdx.x) return;
  int* p = part + c * NCHUNK;
  int run = 0;
  for (int b = 0; b < NCHUNK; b++) { const int t = p[b]; p[b] = run; run += t; }
  ptrs[(size_t)c * (N_NODES + 1) + N_NODES] = run;
}

__global__ __launch_bounds__(256)
void scan3_k(int* __restrict__ ptrs, const int* __restrict__ part)
{
  const int c = blockIdx.y, b = blockIdx.x;
  int* d = ptrs + (size_t)c * (N_NODES + 1) + b * 1024;
  const int base = part[c * NCHUNK + b];
  const int gbase = b * 1024;
  const int i0 = threadIdx.x * 4;
  int v[4];
  #pragma unroll
  for (int j = 0; j < 4; j++) v[j] = (gbase + i0 + j < N_NODES) ? d[i0 + j] : 0;
  const int tsum = v[0] + v[1] + v[2] + v[3];
  __shared__ int sc[256];
  sc[threadIdx.x] = tsum;
  __syncthreads();
  #pragma unroll
  for (int off = 1; off < 256; off <<= 1) {
    const int t = (threadIdx.x >= off) ? sc[threadIdx.x - off] : 0;
    __syncthreads();
    sc[threadIdx.x] += t;
    __syncthreads();
  }
  int run = sc[threadIdx.x] - tsum + base;
  #pragma unroll
  for (int j = 0; j < 4; j++) {
    if (gbase + i0 + j < N_NODES) d[i0 + j] = run;
    run += v[j];
  }
}

// fill stores SOURCE node ids; ptrs become end-offsets
__global__ __launch_bounds__(256)
void fill_k(EdgeCfg cfg, int* __restrict__ ptrs, int* __restrict__ idxs)
{
  const int c = blockIdx.y;
  const int i = blockIdx.x * 256 + threadIdx.x;
  if (i >= cfg.cnt[c]) return;
  const int d = cfg.dst[c][i];
  const int slot = atomicAdd(ptrs + (size_t)c * (N_NODES + 1) + d, 1);
  idxs[idx_base(c) + slot] = cfg.src[c][i];
}

__global__ __launch_bounds__(256)
void copy_k(const float* __restrict__ src, float* __restrict__ dst, int n)
{
  const int i = blockIdx.x * 256 + threadIdx.x;
  if (i < n) dst[i] = src[i];
}

extern "C" void kernel_launch(void* const* d_in, const int* in_sizes, int n_in,
                              void* d_out, int out_size, void* d_ws, size_t ws_size,
                              hipStream_t stream) {
  const float* control   = (const float*)d_in[0];
  const float* turn      = (const float*)d_in[1];
  const float* intersect = (const float*)d_in[2];
  const float* ctrs      = (const float*)d_in[3];
  const float* feats     = (const float*)d_in[4];
  const int*   pre   = (const int*)d_in[5];
  const int*   suc   = (const int*)d_in[6];
  const int*   left  = (const int*)d_in[7];
  const int*   right = (const int*)d_in[8];
  const float* w_in1   = (const float*)d_in[9];
  const float* b_in1   = (const float*)d_in[10];
  const float* w_in2   = (const float*)d_in[11];
  const float* gn_in_g = (const float*)d_in[12];
  const float* gn_in_b = (const float*)d_in[13];
  const float* w_seg1   = (const float*)d_in[14];
  const float* b_seg1   = (const float*)d_in[15];
  const float* w_seg2   = (const float*)d_in[16];
  const float* gn_seg_g = (const float*)d_in[17];
  const float* gn_seg_b = (const float*)d_in[18];
  const float* w_meta    = (const float*)d_in[19];
  const float* gn_meta_g = (const float*)d_in[20];
  const float* gn_meta_b = (const float*)d_in[21];
  const float* ctr_w   = (const float*)d_in[22];
  const float* pre_w   = (const float*)d_in[23];
  const float* suc_w   = (const float*)d_in[24];
  const float* left_w  = (const float*)d_in[25];
  const float* right_w = (const float*)d_in[26];
  const float* norm_g  = (const float*)d_in[27];
  const float* norm_b  = (const float*)d_in[28];
  const float* ctr2_w  = (const float*)d_in[29];
  const float* ctr2_g  = (const float*)d_in[30];
  const float* ctr2_b  = (const float*)d_in[31];

  const size_t NF = (size_t)N_NODES * CDIM;
  char* w = (char*)d_ws;
  float* Ta = (float*)w;  w += NF * 4;           // a-branch
  float* Tb = (float*)w;  w += NF * 4;           // b-branch
  u16* Fb0  = (u16*)w;    w += NF * 2;
  u16* Fb1  = (u16*)w;    w += NF * 2;
  u16* Wt   = (u16*)w;    w += (size_t)(67 * 16384 + 128 * 160) * 2;
  int* ptrs = (int*)w;    w += (size_t)NCLS * (N_NODES + 1) * 4;
  int* idxs = (int*)w;    w += (size_t)(12 * NEP + 2 * NEL) * 4;
  int* part = (int*)w;
  float* out = (float*)d_out;

  EdgeCfg cfg;
  for (int s = 0; s < NSCALE; s++) {
    cfg.dst[s] = pre + (size_t)s * 2 * NEP;     cfg.src[s] = pre + ((size_t)s * 2 + 1) * NEP;     cfg.cnt[s] = NEP;
    cfg.dst[6 + s] = suc + (size_t)s * 2 * NEP; cfg.src[6 + s] = suc + ((size_t)s * 2 + 1) * NEP; cfg.cnt[6 + s] = NEP;
  }
  cfg.dst[12] = left;  cfg.src[12] = left + NEL;  cfg.cnt[12] = NEL;
  cfg.dst[13] = right; cfg.src[13] = right + NEL; cfg.cnt[13] = NEL;

  const dim3 blk(256);
  const dim3 gN((N_NODES + 127) / 128);   // 1563 (prologue)
  const dim3 gL((N_NODES + MROWS - 1) / MROWS);   // 3125 (layers)
  const dim3 gHist((NEP + 255) / 256, NCLS);
  const dim3 gScan(NCHUNK, NCLS);

  // ---- weight prep + CSR build ----
  prep_k<<<dim3(67), blk, 0, stream>>>(w_in2, w_seg2, ctr_w, ctr2_w, left_w, right_w,
                                       pre_w, suc_w, w_meta, Wt);
  (void)hipMemsetAsync(ptrs, 0, (size_t)NCLS * (N_NODES + 1) * sizeof(int), stream);
  hist_k<<<gHist, blk, 0, stream>>>(cfg, ptrs);
  scan1_k<<<gScan, blk, 0, stream>>>(ptrs, part);
  scan2_k<<<dim3(NCLS), dim3(64), 0, stream>>>(part, ptrs);
  scan3_k<<<gScan, blk, 0, stream>>>(ptrs, part);
  fill_k<<<gHist, blk, 0, stream>>>(cfg, ptrs, idxs);

  // ---- prologue: a-branch -> Ta, b-branch -> Tb, meta -> Fb0 (bf16 only) ----
  mm_k<P_TWO, E_GN><<<gN, blk, 0, stream>>>(N_NODES, 128, ctrs, nullptr,
      w_in1, b_in1, nullptr, Wt + 0 * 16384, Ta, nullptr, gn_in_g, gn_in_b);
  mm_k<P_TWO, E_GN><<<gN, blk, 0, stream>>>(N_NODES, 128, feats, nullptr,
      w_seg1, b_seg1, nullptr, Wt + 1 * 16384, Tb, nullptr, gn_seg_g, gn_seg_b);
  mm_k<P_META, E_GN | E_RELU><<<gN, blk, 0, stream>>>(N_NODES, 160, Ta, Tb,
      turn, control, intersect, Wt + 66 * 16384, nullptr, Fb0, gn_meta_g, gn_meta_b);

  // ---- 4 fused layers (double-buffered bf16 features) ----
  for (int i = 0; i < 4; i++) {
    const u16* Fin = (i & 1) ? Fb1 : Fb0;
    u16* Fout      = (i & 1) ? Fb0 : Fb1;
    layer_k<<<gL, blk, 0, stream>>>(Fin, Fout, (i == 3) ? out : nullptr,
        ptrs, idxs, Wt, i,
        norm_g + i * 128, norm_b + i * 128, ctr2_g + i * 128, ctr2_b + i * 128);
  }

  copy_k<<<dim3((2 * N_NODES + 255) / 256), blk, 0, stream>>>(ctrs, out + NF, 2 * N_NODES);
}